// Round 6
// baseline (44.297 us; speedup 1.0000x reference)
//
#include <hip/hip_runtime.h>

#define W 512

// ---------------------------------------------------------------------------
// Fused kernel, 1024 threads = 16 waves per block.
//
// Blocks [0, B*4):  column scan (channel 1), float4-vectorized, SINGLE-pass.
//   Tile = 128 cols x 512 rows. Thread (c4 = t&31, seg = t>>5) owns columns
//   [4*c4, 4*c4+4) x rows [16*seg, 16*seg+16).
//   Phase 1: 16 strided float4 loads -> in-register inclusive scan.
//   The 16 scanned float4 values are PINNED in VGPRs via opaque asm so the
//   compiler cannot rematerialize the loads after the barrier (it did in
//   R2-R4, silently creating a 2-pass kernel: VGPR=56, 48 VMEM/thread).
//   LDS exchange of segment totals; exclusive offset per column.
//   Phase 2: 16 pure stores of v[y] + off. 32 VMEM/thread total.
//
// Blocks [B*4, ...): row scan (channel 0). One wave per 512-float row.
//   Lane l owns elements [8l, 8l+8) via 2x float4; local scan of 8 +
//   6-step __shfl_up wave scan.
// ---------------------------------------------------------------------------
__global__ __launch_bounds__(1024) void fused_scan_kernel(const float* __restrict__ in,
                                                          float* __restrict__ out,
                                                          int B) {
    __shared__ float4 sums[32][32];    // [segment][c4]  (16 KiB)

    const int nColBlocks = B * 4;      // 128-col tiles per image

    if ((int)blockIdx.x < nColBlocks) {
        // ----- column scan (channel 1), single pass, register-resident -----
        const int tile = blockIdx.x & 3;
        const int b    = blockIdx.x >> 2;
        const int c4   = threadIdx.x & 31;     // float4 column group
        const int seg  = threadIdx.x >> 5;     // 0..31, 16 rows each
        const int col  = tile * 128 + c4 * 4;

        const size_t base = (size_t)b * (2 * W * W) + (size_t)(W * W) + col
                          + (size_t)(seg * 16) * W;
        const float4* __restrict__ p = (const float4*)(in + base);
        float4*       __restrict__ q = (float4*)(out + base);
        const int strideV = W / 4;             // row stride in float4 units

        float4 v[16];
#pragma unroll
        for (int y = 0; y < 16; ++y) v[y] = p[(size_t)y * strideV];

        // in-register inclusive scan of the segment
        float4 acc = make_float4(0.f, 0.f, 0.f, 0.f);
#pragma unroll
        for (int y = 0; y < 16; ++y) {
            acc.x += v[y].x; acc.y += v[y].y; acc.z += v[y].z; acc.w += v[y].w;
            v[y] = acc;
        }

        // Pin scanned values in VGPRs: opaque to the optimizer, so it must
        // keep them live across the barrier instead of reloading from global.
#pragma unroll
        for (int y = 0; y < 16; ++y) {
            asm volatile("" : "+v"(v[y].x), "+v"(v[y].y), "+v"(v[y].z), "+v"(v[y].w));
        }

        sums[seg][c4] = acc;
        __syncthreads();

        // exclusive offset = sum of preceding segments' totals for this column
        float4 off = make_float4(0.f, 0.f, 0.f, 0.f);
        for (int s = 0; s < seg; ++s) {
            float4 t = sums[s][c4];
            off.x += t.x; off.y += t.y; off.z += t.z; off.w += t.w;
        }

        // Phase 2: pure stores
#pragma unroll
        for (int y = 0; y < 16; ++y) {
            float4 r = make_float4(v[y].x + off.x, v[y].y + off.y,
                                   v[y].z + off.z, v[y].w + off.w);
            q[(size_t)y * strideV] = r;
        }
    } else {
        // ----- row scan (channel 0) -----
        const int tx  = threadIdx.x & 63;      // lane
        const int wv  = threadIdx.x >> 6;      // wave 0..15
        const int rb  = (int)blockIdx.x - nColBlocks;
        const int row = rb * 16 + wv;          // global row in [0, B*W)
        const int b   = row >> 9;              // / 512
        const int y   = row & 511;             // % 512
        const size_t base = (size_t)b * (2 * W * W) + (size_t)y * W;

        const float4* __restrict__ ip = (const float4*)(in + base);
        float4 v0 = ip[tx * 2 + 0];
        float4 v1 = ip[tx * 2 + 1];

        float a0 = v0.x;
        float a1 = a0 + v0.y;
        float a2 = a1 + v0.z;
        float a3 = a2 + v0.w;
        float a4 = a3 + v1.x;
        float a5 = a4 + v1.y;
        float a6 = a5 + v1.z;
        float a7 = a6 + v1.w;

        float total = a7;
        float inc = total;
#pragma unroll
        for (int o = 1; o < 64; o <<= 1) {
            float t = __shfl_up(inc, o, 64);
            if (tx >= o) inc += t;
        }
        const float excl = inc - total;

        float4 r0 = make_float4(a0 + excl, a1 + excl, a2 + excl, a3 + excl);
        float4 r1 = make_float4(a4 + excl, a5 + excl, a6 + excl, a7 + excl);

        float4* __restrict__ op = (float4*)(out + base);
        op[tx * 2 + 0] = r0;
        op[tx * 2 + 1] = r1;
    }
}

extern "C" void kernel_launch(void* const* d_in, const int* in_sizes, int n_in,
                              void* d_out, int out_size, void* d_ws, size_t ws_size,
                              hipStream_t stream) {
    const float* in = (const float*)d_in[0];
    float* out = (float*)d_out;

    const int B = in_sizes[0] / (2 * W * W);   // 64
    const int colBlocks = B * 4;               // 256  (128-col float4 tiles)
    const int rowBlocks = (B * W) / 16;        // 2048 (16 rows per block)

    fused_scan_kernel<<<colBlocks + rowBlocks, 1024, 0, stream>>>(in, out, B);
}